// Round 2
// baseline (972.878 us; speedup 1.0000x reference)
//
#include <hip/hip_runtime.h>
#include <math.h>

#define N_TOK 8192
#define C_DIM 1024
#define D_DIM 3072
#define E_NUM 8

typedef unsigned short u16;
typedef unsigned int u32;
typedef __attribute__((ext_vector_type(8))) short bf16x8;
typedef __attribute__((ext_vector_type(4))) float f32x4;

__device__ __forceinline__ u16 f2bf(float f) {
  u32 u = __builtin_bit_cast(unsigned int, f);
  u = (u + 0x7FFFu + ((u >> 16) & 1u)) >> 16;
  return (u16)u;
}

__device__ __forceinline__ void gl_lds16(const void* g, void* l) {
  __builtin_amdgcn_global_load_lds(
      (const __attribute__((address_space(1))) unsigned int*)g,
      (__attribute__((address_space(3))) unsigned int*)l, 16, 0, 0);
}

// ---------------- init: zero output (incl aux loss) + counters ----------------
__global__ void zero_init_kernel(float* __restrict__ out, int n, int* __restrict__ cnt) {
  int i = blockIdx.x * 256 + threadIdx.x;
  if (i < n) out[i] = 0.0f;
  if (i < E_NUM) cnt[i] = 0;
}

// ---------------- convert x to bf16 ----------------
__global__ void convert_x_kernel(const float* __restrict__ x, u16* __restrict__ xbf) {
  int i = (blockIdx.x * 256 + threadIdx.x) * 8;
  float4 a = *(const float4*)(x + i);
  float4 b = *(const float4*)(x + i + 4);
  union { u16 s[8]; uint4 v; } o;
  o.s[0] = f2bf(a.x); o.s[1] = f2bf(a.y); o.s[2] = f2bf(a.z); o.s[3] = f2bf(a.w);
  o.s[4] = f2bf(b.x); o.s[5] = f2bf(b.y); o.s[6] = f2bf(b.z); o.s[7] = f2bf(b.w);
  *(uint4*)(xbf + i) = o.v;
}

// ---------------- W1 [E][C][D] f32 -> W1t [E][D][C] bf16 ----------------
__global__ void transpose_w1_kernel(const float* __restrict__ W1, u16* __restrict__ W1t) {
  __shared__ float t[32][33];
  const int e = blockIdx.z;
  const int d0 = blockIdx.x * 32, c0 = blockIdx.y * 32;
  const int tx = threadIdx.x, ty = threadIdx.y;
#pragma unroll
  for (int i = 0; i < 4; i++)
    t[ty + i * 8][tx] = W1[((size_t)e * C_DIM + c0 + ty + i * 8) * D_DIM + d0 + tx];
  __syncthreads();
#pragma unroll
  for (int i = 0; i < 4; i++)
    W1t[((size_t)e * D_DIM + d0 + ty + i * 8) * C_DIM + c0 + tx] = f2bf(t[tx][ty + i * 8]);
}

// ---------------- W2 [E][D][C] f32 -> W2t [E][C][D] bf16 ----------------
__global__ void transpose_w2_kernel(const float* __restrict__ W2, u16* __restrict__ W2t) {
  __shared__ float t[32][33];
  const int e = blockIdx.z;
  const int c0 = blockIdx.x * 32, d0 = blockIdx.y * 32;
  const int tx = threadIdx.x, ty = threadIdx.y;
#pragma unroll
  for (int i = 0; i < 4; i++)
    t[ty + i * 8][tx] = W2[((size_t)e * D_DIM + d0 + ty + i * 8) * C_DIM + c0 + tx];
  __syncthreads();
#pragma unroll
  for (int i = 0; i < 4; i++)
    W2t[((size_t)e * C_DIM + c0 + ty + i * 8) * D_DIM + d0 + tx] = f2bf(t[tx][ty + i * 8]);
}

// ---------------- router: logits, softmax, top-2, scatter ----------------
__global__ void router_kernel(const float* __restrict__ x, const float* __restrict__ rw,
                              int* __restrict__ cnt, int* __restrict__ list,
                              float* __restrict__ wl) {
  const int lane = threadIdx.x & 63;
  const int n = blockIdx.x * 4 + (threadIdx.x >> 6);
  const float* xr = x + (size_t)n * C_DIM;
  double acc[E_NUM];
#pragma unroll
  for (int e = 0; e < E_NUM; e++) acc[e] = 0.0;
  for (int c = lane; c < C_DIM; c += 64) {
    float xv = xr[c];
#pragma unroll
    for (int e = 0; e < E_NUM; e++) acc[e] += (double)xv * (double)rw[e * C_DIM + c];
  }
#pragma unroll
  for (int e = 0; e < E_NUM; e++) {
    double v = acc[e];
#pragma unroll
    for (int off = 32; off > 0; off >>= 1) v += __shfl_down(v, off, 64);
    acc[e] = v;
  }
  if (lane == 0) {
    int i0 = 0;
#pragma unroll
    for (int e = 1; e < E_NUM; e++) if (acc[e] > acc[i0]) i0 = e;
    int i1 = (i0 == 0) ? 1 : 0;
#pragma unroll
    for (int e = 0; e < E_NUM; e++) if (e != i0 && acc[e] > acc[i1]) i1 = e;
    double d = acc[i0] - acc[i1];          // >= 0
    double w0 = 1.0 / (1.0 + exp(-d));     // p0/(p0+p1)
    double w1 = 1.0 - w0;
    int p0 = atomicAdd(&cnt[i0], 1);
    list[i0 * N_TOK + p0] = n; wl[i0 * N_TOK + p0] = (float)w0;
    int p1 = atomicAdd(&cnt[i1], 1);
    list[i1 * N_TOK + p1] = n; wl[i1 * N_TOK + p1] = (float)w1;
  }
}

// ---------------- prefix sum of counts ----------------
__global__ void prefix_kernel(const int* __restrict__ cnt, int* __restrict__ rowbase) {
  if (threadIdx.x == 0) {
    int s = 0;
    for (int e = 0; e < E_NUM; e++) { rowbase[e] = s; s += cnt[e]; }
  }
}

// ---------------- GEMM1: h = gelu(Xg @ W1[e] + b1[e]) -> bf16 ----------------
__global__ __launch_bounds__(256) void gemm1_kernel(
    const u16* __restrict__ Xbf, const u16* __restrict__ W1t, const float* __restrict__ b1,
    const int* __restrict__ list, const int* __restrict__ cnt, const int* __restrict__ rowbase,
    u16* __restrict__ h) {
  const int e = blockIdx.z;
  const int count = cnt[e];
  const int m0 = blockIdx.x * 128;
  if (m0 >= count) return;
  const int n0 = blockIdx.y * 128;

  __shared__ __align__(16) u16 ldsA[128 * 32];
  __shared__ __align__(16) u16 ldsB[128 * 32];

  const int tid = threadIdx.x;
  const int lane = tid & 63;
  const int wid = tid >> 6;
  const int wm = (wid >> 1) * 64;
  const int wn = (wid & 1) * 64;

  const int r0 = tid >> 2;
  const int colb = (tid & 3) * 8;
  const int* lst = list + e * N_TOK;
  const int tok0 = lst[min(m0 + r0, count - 1)];
  const int tok1 = lst[min(m0 + r0 + 64, count - 1)];
  const u16* asrc0 = Xbf + (size_t)tok0 * C_DIM + colb;
  const u16* asrc1 = Xbf + (size_t)tok1 * C_DIM + colb;
  const u16* bsrc0 = W1t + ((size_t)e * D_DIM + n0 + r0) * C_DIM + colb;
  const u16* bsrc1 = W1t + ((size_t)e * D_DIM + n0 + r0 + 64) * C_DIM + colb;
  u16* lA = ldsA + tid * 8;
  u16* lB = ldsB + tid * 8;

  f32x4 acc[4][4];
#pragma unroll
  for (int i = 0; i < 4; i++)
#pragma unroll
    for (int j = 0; j < 4; j++) acc[i][j] = {0.f, 0.f, 0.f, 0.f};

  const u16* pa = ldsA + (wm + (lane & 15)) * 32 + (lane >> 4) * 8;
  const u16* pb = ldsB + (wn + (lane & 15)) * 32 + (lane >> 4) * 8;

  for (int k0 = 0; k0 < C_DIM; k0 += 32) {
    gl_lds16(asrc0, lA);
    gl_lds16(asrc1, lA + 2048);
    gl_lds16(bsrc0, lB);
    gl_lds16(bsrc1, lB + 2048);
    asrc0 += 32; asrc1 += 32; bsrc0 += 32; bsrc1 += 32;
    __syncthreads();
    bf16x8 av[4], bv[4];
#pragma unroll
    for (int i = 0; i < 4; i++) av[i] = *(const bf16x8*)(pa + i * 16 * 32);
#pragma unroll
    for (int i = 0; i < 4; i++) bv[i] = *(const bf16x8*)(pb + i * 16 * 32);
#pragma unroll
    for (int i = 0; i < 4; i++)
#pragma unroll
      for (int j = 0; j < 4; j++)
        acc[i][j] = __builtin_amdgcn_mfma_f32_16x16x32_bf16(av[i], bv[j], acc[i][j], 0, 0, 0);
    __syncthreads();
  }

  const int rb = rowbase[e];
#pragma unroll
  for (int i = 0; i < 4; i++) {
    const int rloc = wm + i * 16 + (lane >> 4) * 4;
#pragma unroll
    for (int j = 0; j < 4; j++) {
      const int col = n0 + wn + j * 16 + (lane & 15);
      const float bias = b1[e * D_DIM + col];
#pragma unroll
      for (int r = 0; r < 4; r++) {
        const int m = m0 + rloc + r;
        if (m < count) {
          float v = acc[i][j][r] + bias;
          float g = 0.5f * v * (1.0f + erff(v * 0.70710678118654752f));
          h[(size_t)(rb + m) * D_DIM + col] = f2bf(g);
        }
      }
    }
  }
}

// ---------------- GEMM2: out += w * (h @ W2[e] + b2[e]) ----------------
__global__ __launch_bounds__(256) void gemm2_kernel(
    const u16* __restrict__ h, const u16* __restrict__ W2t, const float* __restrict__ b2,
    const int* __restrict__ list, const float* __restrict__ wl, const int* __restrict__ cnt,
    const int* __restrict__ rowbase, float* __restrict__ out) {
  const int e = blockIdx.z;
  const int count = cnt[e];
  const int m0 = blockIdx.x * 128;
  if (m0 >= count) return;
  const int n0 = blockIdx.y * 128;

  __shared__ __align__(16) u16 ldsA[128 * 32];
  __shared__ __align__(16) u16 ldsB[128 * 32];

  const int tid = threadIdx.x;
  const int lane = tid & 63;
  const int wid = tid >> 6;
  const int wm = (wid >> 1) * 64;
  const int wn = (wid & 1) * 64;

  const int r0 = tid >> 2;
  const int colb = (tid & 3) * 8;
  const int rb = rowbase[e];
  const u16* asrc0 = h + (size_t)(rb + min(m0 + r0, count - 1)) * D_DIM + colb;
  const u16* asrc1 = h + (size_t)(rb + min(m0 + r0 + 64, count - 1)) * D_DIM + colb;
  const u16* bsrc0 = W2t + ((size_t)e * C_DIM + n0 + r0) * D_DIM + colb;
  const u16* bsrc1 = W2t + ((size_t)e * C_DIM + n0 + r0 + 64) * D_DIM + colb;
  u16* lA = ldsA + tid * 8;
  u16* lB = ldsB + tid * 8;

  f32x4 acc[4][4];
#pragma unroll
  for (int i = 0; i < 4; i++)
#pragma unroll
    for (int j = 0; j < 4; j++) acc[i][j] = {0.f, 0.f, 0.f, 0.f};

  const u16* pa = ldsA + (wm + (lane & 15)) * 32 + (lane >> 4) * 8;
  const u16* pb = ldsB + (wn + (lane & 15)) * 32 + (lane >> 4) * 8;

  for (int k0 = 0; k0 < D_DIM; k0 += 32) {
    gl_lds16(asrc0, lA);
    gl_lds16(asrc1, lA + 2048);
    gl_lds16(bsrc0, lB);
    gl_lds16(bsrc1, lB + 2048);
    asrc0 += 32; asrc1 += 32; bsrc0 += 32; bsrc1 += 32;
    __syncthreads();
    bf16x8 av[4], bv[4];
#pragma unroll
    for (int i = 0; i < 4; i++) av[i] = *(const bf16x8*)(pa + i * 16 * 32);
#pragma unroll
    for (int i = 0; i < 4; i++) bv[i] = *(const bf16x8*)(pb + i * 16 * 32);
#pragma unroll
    for (int i = 0; i < 4; i++)
#pragma unroll
      for (int j = 0; j < 4; j++)
        acc[i][j] = __builtin_amdgcn_mfma_f32_16x16x32_bf16(av[i], bv[j], acc[i][j], 0, 0, 0);
    __syncthreads();
  }

  const int* lst = list + e * N_TOK;
  const float* wlst = wl + e * N_TOK;
#pragma unroll
  for (int i = 0; i < 4; i++) {
    const int rloc = wm + i * 16 + (lane >> 4) * 4;
#pragma unroll
    for (int j = 0; j < 4; j++) {
      const int col = n0 + wn + j * 16 + (lane & 15);
      const float bias = b2[e * C_DIM + col];
#pragma unroll
      for (int r = 0; r < 4; r++) {
        const int m = m0 + rloc + r;
        if (m < count) {
          const int t = lst[m];
          const float w = wlst[m];
          atomicAdd(out + (size_t)t * C_DIM + col, w * (acc[i][j][r] + bias));
        }
      }
    }
  }
}

extern "C" void kernel_launch(void* const* d_in, const int* in_sizes, int n_in,
                              void* d_out, int out_size, void* d_ws, size_t ws_size,
                              hipStream_t stream) {
  const float* x  = (const float*)d_in[0];
  const float* rw = (const float*)d_in[1];
  const float* W1 = (const float*)d_in[2];
  const float* b1 = (const float*)d_in[3];
  const float* W2 = (const float*)d_in[4];
  const float* b2 = (const float*)d_in[5];
  float* out = (float*)d_out;

  char* ws = (char*)d_ws;
  u16* W1t    = (u16*)(ws);                      // 50,331,648 B
  u16* W2t    = (u16*)(ws + 50331648);           // 50,331,648 B
  u16* Xbf    = (u16*)(ws + 100663296);          // 16,777,216 B
  int* cnt    = (int*)(ws + 117440512);          // 256 B
  int* rowbase= (int*)(ws + 117440768);          // 256 B
  int* list   = (int*)(ws + 117441024);          // 262,144 B
  float* wl   = (float*)(ws + 117703168);        // 262,144 B
  u16* h      = (u16*)(ws + 117965312);          // 100,663,296 B -> end 218,628,608

  zero_init_kernel<<<(out_size + 255) / 256, 256, 0, stream>>>(out, out_size, cnt);
  convert_x_kernel<<<(N_TOK * C_DIM) / (256 * 8), 256, 0, stream>>>(x, Xbf);
  transpose_w1_kernel<<<dim3(D_DIM / 32, C_DIM / 32, E_NUM), dim3(32, 8), 0, stream>>>(W1, W1t);
  transpose_w2_kernel<<<dim3(C_DIM / 32, D_DIM / 32, E_NUM), dim3(32, 8), 0, stream>>>(W2, W2t);
  router_kernel<<<N_TOK / 4, 256, 0, stream>>>(x, rw, cnt, list, wl);
  prefix_kernel<<<1, 64, 0, stream>>>(cnt, rowbase);
  gemm1_kernel<<<dim3(N_TOK / 128, D_DIM / 128, E_NUM), 256, 0, stream>>>(Xbf, W1t, b1, list, cnt, rowbase, h);
  gemm2_kernel<<<dim3(N_TOK / 128, C_DIM / 128, E_NUM), 256, 0, stream>>>(h, W2t, b2, list, wl, cnt, rowbase, out);
}

// Round 3
// 887.187 us; speedup vs baseline: 1.0966x; 1.0966x over previous
//
#include <hip/hip_runtime.h>
#include <math.h>

#define N_TOK 8192
#define C_DIM 1024
#define D_DIM 3072
#define E_NUM 8
#define MAXB 72

typedef unsigned short u16;
typedef unsigned int u32;
typedef __attribute__((ext_vector_type(8))) short bf16x8;
typedef __attribute__((ext_vector_type(4))) float f32x4;

__device__ __forceinline__ u16 f2bf(float f) {
  u32 u = __builtin_bit_cast(unsigned int, f);
  u = (u + 0x7FFFu + ((u >> 16) & 1u)) >> 16;
  return (u16)u;
}

__device__ __forceinline__ void gl_lds16(const void* g, void* l) {
  __builtin_amdgcn_global_load_lds(
      (const __attribute__((address_space(1))) unsigned int*)g,
      (__attribute__((address_space(3))) unsigned int*)l, 16, 0, 0);
}

// fused counted-vmcnt wait + barrier (no gap for code motion; "memory" fences LDS/VMEM ops)
template<int N> __device__ __forceinline__ void wait_bar() {
  if constexpr (N == 0) asm volatile("s_waitcnt vmcnt(0)\n\ts_barrier" ::: "memory");
  else if constexpr (N == 3) asm volatile("s_waitcnt vmcnt(3)\n\ts_barrier" ::: "memory");
  else asm volatile("s_waitcnt vmcnt(4)\n\ts_barrier" ::: "memory");
}

// ---------------- init: zero output (incl aux loss) + counters ----------------
__global__ void zero_init_kernel(float* __restrict__ out, int n, int* __restrict__ cnt) {
  int i = blockIdx.x * 256 + threadIdx.x;
  if (i < n) out[i] = 0.0f;
  if (i < E_NUM) cnt[i] = 0;
}

// ---------------- convert x to bf16 ----------------
__global__ void convert_x_kernel(const float* __restrict__ x, u16* __restrict__ xbf) {
  int i = (blockIdx.x * 256 + threadIdx.x) * 8;
  float4 a = *(const float4*)(x + i);
  float4 b = *(const float4*)(x + i + 4);
  union { u16 s[8]; uint4 v; } o;
  o.s[0] = f2bf(a.x); o.s[1] = f2bf(a.y); o.s[2] = f2bf(a.z); o.s[3] = f2bf(a.w);
  o.s[4] = f2bf(b.x); o.s[5] = f2bf(b.y); o.s[6] = f2bf(b.z); o.s[7] = f2bf(b.w);
  *(uint4*)(xbf + i) = o.v;
}

// ---------------- W1 [E][C][D] f32 -> W1t [E][D][C] bf16 ----------------
__global__ void transpose_w1_kernel(const float* __restrict__ W1, u16* __restrict__ W1t) {
  __shared__ float t[32][33];
  const int e = blockIdx.z;
  const int d0 = blockIdx.x * 32, c0 = blockIdx.y * 32;
  const int tx = threadIdx.x, ty = threadIdx.y;
#pragma unroll
  for (int i = 0; i < 4; i++)
    t[ty + i * 8][tx] = W1[((size_t)e * C_DIM + c0 + ty + i * 8) * D_DIM + d0 + tx];
  __syncthreads();
#pragma unroll
  for (int i = 0; i < 4; i++)
    W1t[((size_t)e * D_DIM + d0 + ty + i * 8) * C_DIM + c0 + tx] = f2bf(t[tx][ty + i * 8]);
}

// ---------------- W2 [E][D][C] f32 -> W2t [E][C][D] bf16 ----------------
__global__ void transpose_w2_kernel(const float* __restrict__ W2, u16* __restrict__ W2t) {
  __shared__ float t[32][33];
  const int e = blockIdx.z;
  const int c0 = blockIdx.x * 32, d0 = blockIdx.y * 32;
  const int tx = threadIdx.x, ty = threadIdx.y;
#pragma unroll
  for (int i = 0; i < 4; i++)
    t[ty + i * 8][tx] = W2[((size_t)e * D_DIM + d0 + ty + i * 8) * C_DIM + c0 + tx];
  __syncthreads();
#pragma unroll
  for (int i = 0; i < 4; i++)
    W2t[((size_t)e * C_DIM + c0 + ty + i * 8) * D_DIM + d0 + tx] = f2bf(t[tx][ty + i * 8]);
}

// ---------------- router: logits (fp64), top-2, scatter ----------------
__global__ void router_kernel(const float* __restrict__ x, const float* __restrict__ rw,
                              int* __restrict__ cnt, int* __restrict__ list,
                              float* __restrict__ wl) {
  const int lane = threadIdx.x & 63;
  const int n = blockIdx.x * 4 + (threadIdx.x >> 6);
  const float* xr = x + (size_t)n * C_DIM;
  double acc[E_NUM];
#pragma unroll
  for (int e = 0; e < E_NUM; e++) acc[e] = 0.0;
  for (int c = lane; c < C_DIM; c += 64) {
    float xv = xr[c];
#pragma unroll
    for (int e = 0; e < E_NUM; e++) acc[e] += (double)xv * (double)rw[e * C_DIM + c];
  }
#pragma unroll
  for (int e = 0; e < E_NUM; e++) {
    double v = acc[e];
#pragma unroll
    for (int off = 32; off > 0; off >>= 1) v += __shfl_down(v, off, 64);
    acc[e] = v;
  }
  if (lane == 0) {
    int i0 = 0;
#pragma unroll
    for (int e = 1; e < E_NUM; e++) if (acc[e] > acc[i0]) i0 = e;
    int i1 = (i0 == 0) ? 1 : 0;
#pragma unroll
    for (int e = 0; e < E_NUM; e++) if (e != i0 && acc[e] > acc[i1]) i1 = e;
    double d = acc[i0] - acc[i1];          // >= 0
    double w0 = 1.0 / (1.0 + exp(-d));     // p0/(p0+p1)
    double w1 = 1.0 - w0;
    int p0 = atomicAdd(&cnt[i0], 1);
    list[i0 * N_TOK + p0] = n; wl[i0 * N_TOK + p0] = (float)w0;
    int p1 = atomicAdd(&cnt[i1], 1);
    list[i1 * N_TOK + p1] = n; wl[i1 * N_TOK + p1] = (float)w1;
  }
}

// ---------------- prefix sum + block table (BM=256 segments) ----------------
__global__ void prefix_kernel(const int* __restrict__ cnt, int* __restrict__ rowbase,
                              int* __restrict__ btab) {
  if (threadIdx.x == 0) {
    int s = 0, nb = 0;
    for (int e = 0; e < E_NUM; e++) {
      rowbase[e] = s;
      for (int m0 = 0; m0 < cnt[e]; m0 += 256) { btab[2 * nb] = e; btab[2 * nb + 1] = m0; nb++; }
      s += cnt[e];
    }
    for (; nb < MAXB; nb++) { btab[2 * nb] = -1; btab[2 * nb + 1] = 0; }
  }
}

// ---------------- 8-wave 256-row deep-pipelined GEMM (T2+T3+T4+T5) ----------------
// EPI=1: h = gelu(Xg @ W1t^T + b1)    A=Xbf gathered rows, Wt=[E][D][C], N=D
// EPI=2: out += w*(h @ W2t^T + b2)    A=h contiguous rows,  Wt=[E][C][D], N=C
template<int BM, int BN, int EPI>
__global__ __launch_bounds__(512, 2) void gemm8p_kernel(
    const u16* __restrict__ A, const u16* __restrict__ Wt, const float* __restrict__ bias_,
    const int* __restrict__ btab, const int* __restrict__ cnt, const int* __restrict__ rowbase,
    const int* __restrict__ list, const float* __restrict__ wl,
    u16* __restrict__ hout, float* __restrict__ out) {
  constexpr int K    = (EPI == 1) ? C_DIM : D_DIM;
  constexpr int NTOT = (EPI == 1) ? D_DIM : C_DIM;
  constexpr int NT = K / 64;       // K-tiles
  constexpr int TM = BM / 2;       // 128 (2 M-waves)
  constexpr int TN = BN / 4;       // 64 / 32 (4 N-waves)
  constexpr int MR = TM / 16;      // 8
  constexpr int NR = TN / 16;      // 4 / 2
  constexpr int RA = BM / 128;     // stage reps A = 2
  constexpr int RB = BN / 128;     // 2 / 1
  constexpr int VS = RA + RB;      // one stage-call in flight

  __shared__ __align__(16) u16 ldsA[4 * BM * 32];  // [buf][khalf][BM][32]
  __shared__ __align__(16) u16 ldsB[4 * BN * 32];

  const int e = btab[blockIdx.x * 2];
  if (e < 0) return;
  const int m0 = btab[blockIdx.x * 2 + 1];
  const int count = cnt[e];
  const int rb = rowbase[e];
  const int n0 = blockIdx.y * BN;

  const int tid = threadIdx.x;
  const int lane = tid & 63;
  const int wid = tid >> 6;
  const int wr = wid >> 2, wc = wid & 3;
  const int l15 = lane & 15, l4 = lane >> 4;

  // staging: thread handles 16B chunk c = tid + r*512; row=c>>2, pos=c&3.
  // T2 swizzle (involution): source chunk = pos ^ ((row>>1)&3); LDS dest stays linear.
  const int cs8 = ((tid & 3) ^ ((tid >> 3) & 3)) * 8;
  const int* lst = list + e * N_TOK;
  const u16* aptrs[RA];
#pragma unroll
  for (int r = 0; r < RA; r++) {
    const int arow = (tid + r * 512) >> 2;
    const int mm = min(m0 + arow, count - 1);
    const size_t rowi = (EPI == 1) ? (size_t)lst[mm] : (size_t)(rb + mm);
    aptrs[r] = A + rowi * K + cs8;
  }
  const u16* bptrs[RB];
#pragma unroll
  for (int r = 0; r < RB; r++) {
    const int brow = (tid + r * 512) >> 2;
    bptrs[r] = Wt + ((size_t)e * NTOT + n0 + brow) * K + cs8;
  }

  // fragment read offsets (swizzled): row*32 + (chunk ^ (row>>1)&3)*8
  const int swz = (l15 >> 1) & 3;
  const int paoff = (wr * TM + l15) * 32 + ((l4 ^ swz) * 8);
  const int pboff = (wc * TN + l15) * 32 + ((l4 ^ swz) * 8);

  f32x4 acc[MR][NR];
#pragma unroll
  for (int i = 0; i < MR; i++)
#pragma unroll
    for (int j = 0; j < NR; j++) acc[i][j] = {0.f, 0.f, 0.f, 0.f};

  auto STAGE = [&](int kt, int s, int b) {
    u16* da = ldsA + (b * 2 + s) * (BM * 32) + tid * 8;
    u16* db = ldsB + (b * 2 + s) * (BN * 32) + tid * 8;
    const int ko = kt * 64 + s * 32;
#pragma unroll
    for (int r = 0; r < RA; r++) gl_lds16(aptrs[r] + ko, da + r * 4096);
#pragma unroll
    for (int r = 0; r < RB; r++) gl_lds16(bptrs[r] + ko, db + r * 4096);
  };

  auto PHASE = [&](int b, int s) {
    const u16* pa = ldsA + (b * 2 + s) * (BM * 32) + paoff;
    const u16* pb = ldsB + (b * 2 + s) * (BN * 32) + pboff;
    bf16x8 av[MR], bv[NR];
#pragma unroll
    for (int i = 0; i < MR; i++) av[i] = *(const bf16x8*)(pa + i * 512);
#pragma unroll
    for (int j = 0; j < NR; j++) bv[j] = *(const bf16x8*)(pb + j * 512);
    __builtin_amdgcn_s_setprio(1);
#pragma unroll
    for (int i = 0; i < MR; i++)
#pragma unroll
      for (int j = 0; j < NR; j++)
        acc[i][j] = __builtin_amdgcn_mfma_f32_16x16x32_bf16(av[i], bv[j], acc[i][j], 0, 0, 0);
    __builtin_amdgcn_s_setprio(0);
  };

  // prologue: tile 0 both k-halves into buf0; k0 must land, k1 may fly
  STAGE(0, 0, 0);
  STAGE(0, 1, 0);
  wait_bar<VS>();

  int b = 0;
  for (int t = 0; t < NT - 1; ++t) {
    STAGE(t + 1, 0, b ^ 1);   // prefetch next tile k0
    PHASE(b, 0);              // compute cur k0
    wait_bar<VS>();           // cur k1 landed (next k0 may fly)
    STAGE(t + 1, 1, b ^ 1);   // prefetch next tile k1
    PHASE(b, 1);              // compute cur k1
    wait_bar<VS>();           // next k0 landed (next k1 may fly)
    b ^= 1;
  }
  PHASE(b, 0);
  wait_bar<0>();              // last tile k1 fully landed
  PHASE(b, 1);

  // ---------------- epilogue ----------------
  if constexpr (EPI == 1) {
#pragma unroll
    for (int i = 0; i < MR; i++) {
      const int rloc = wr * TM + i * 16 + l4 * 4;
#pragma unroll
      for (int j = 0; j < NR; j++) {
        const int col = n0 + wc * TN + j * 16 + l15;
        const float bias = bias_[e * NTOT + col];
#pragma unroll
        for (int r = 0; r < 4; r++) {
          const int m = m0 + rloc + r;
          if (m < count) {
            float v = acc[i][j][r] + bias;
            float g = 0.5f * v * (1.0f + erff(v * 0.70710678118654752f));
            hout[(size_t)(rb + m) * D_DIM + col] = f2bf(g);
          }
        }
      }
    }
  } else {
    const float* wlst = wl + e * N_TOK;
#pragma unroll
    for (int i = 0; i < MR; i++) {
      const int rloc = wr * TM + i * 16 + l4 * 4;
#pragma unroll
      for (int j = 0; j < NR; j++) {
        const int col = n0 + wc * TN + j * 16 + l15;
        const float bias = bias_[e * NTOT + col];
#pragma unroll
        for (int r = 0; r < 4; r++) {
          const int m = m0 + rloc + r;
          if (m < count) {
            const int tk = lst[m];
            atomicAdd(out + (size_t)tk * C_DIM + col, wlst[m] * (acc[i][j][r] + bias));
          }
        }
      }
    }
  }
}

extern "C" void kernel_launch(void* const* d_in, const int* in_sizes, int n_in,
                              void* d_out, int out_size, void* d_ws, size_t ws_size,
                              hipStream_t stream) {
  const float* x  = (const float*)d_in[0];
  const float* rw = (const float*)d_in[1];
  const float* W1 = (const float*)d_in[2];
  const float* b1 = (const float*)d_in[3];
  const float* W2 = (const float*)d_in[4];
  const float* b2 = (const float*)d_in[5];
  float* out = (float*)d_out;

  char* ws = (char*)d_ws;
  u16* W1t    = (u16*)(ws);                      // 50,331,648 B
  u16* W2t    = (u16*)(ws + 50331648);           // 50,331,648 B
  u16* Xbf    = (u16*)(ws + 100663296);          // 16,777,216 B
  int* cnt    = (int*)(ws + 117440512);          // 256 B
  int* rowbase= (int*)(ws + 117440768);          // 256 B
  int* list   = (int*)(ws + 117441024);          // 262,144 B
  float* wl   = (float*)(ws + 117703168);        // 262,144 B
  int* btab   = (int*)(ws + 117965312);          // 1,024 B
  u16* h      = (u16*)(ws + 117966336);          // 100,663,296 B -> end 218,629,632

  zero_init_kernel<<<(out_size + 255) / 256, 256, 0, stream>>>(out, out_size, cnt);
  convert_x_kernel<<<(N_TOK * C_DIM) / (256 * 8), 256, 0, stream>>>(x, Xbf);
  transpose_w1_kernel<<<dim3(D_DIM / 32, C_DIM / 32, E_NUM), dim3(32, 8), 0, stream>>>(W1, W1t);
  transpose_w2_kernel<<<dim3(C_DIM / 32, D_DIM / 32, E_NUM), dim3(32, 8), 0, stream>>>(W2, W2t);
  router_kernel<<<N_TOK / 4, 256, 0, stream>>>(x, rw, cnt, list, wl);
  prefix_kernel<<<1, 64, 0, stream>>>(cnt, rowbase, btab);
  gemm8p_kernel<256, 256, 1><<<dim3(MAXB, D_DIM / 256), 512, 0, stream>>>(
      Xbf, W1t, b1, btab, cnt, rowbase, list, wl, h, out);
  gemm8p_kernel<256, 128, 2><<<dim3(MAXB, C_DIM / 128), 512, 0, stream>>>(
      h, W2t, b2, btab, cnt, rowbase, list, wl, h, out);
}

// Round 4
// 865.005 us; speedup vs baseline: 1.1247x; 1.0256x over previous
//
#include <hip/hip_runtime.h>
#include <math.h>

#define N_TOK 8192
#define C_DIM 1024
#define D_DIM 3072
#define E_NUM 8
#define MAXB 72

typedef unsigned short u16;
typedef unsigned int u32;
typedef __attribute__((ext_vector_type(8))) short bf16x8;
typedef __attribute__((ext_vector_type(4))) float f32x4;

__device__ __forceinline__ u16 f2bf(float f) {
  u32 u = __builtin_bit_cast(unsigned int, f);
  u = (u + 0x7FFFu + ((u >> 16) & 1u)) >> 16;
  return (u16)u;
}

__device__ __forceinline__ void gl_lds16(const void* g, void* l) {
  __builtin_amdgcn_global_load_lds(
      (const __attribute__((address_space(1))) unsigned int*)g,
      (__attribute__((address_space(3))) unsigned int*)l, 16, 0, 0);
}

// fused counted-vmcnt wait + barrier (asm so the compiler can't drain vmcnt to 0)
template<int N> __device__ __forceinline__ void wait_bar() {
  if constexpr (N == 0)  asm volatile("s_waitcnt vmcnt(0)\n\ts_barrier" ::: "memory");
  else if constexpr (N == 3)  asm volatile("s_waitcnt vmcnt(3)\n\ts_barrier" ::: "memory");
  else if constexpr (N == 4)  asm volatile("s_waitcnt vmcnt(4)\n\ts_barrier" ::: "memory");
  else if constexpr (N == 6)  asm volatile("s_waitcnt vmcnt(6)\n\ts_barrier" ::: "memory");
  else if constexpr (N == 8)  asm volatile("s_waitcnt vmcnt(8)\n\ts_barrier" ::: "memory");
  else if constexpr (N == 9)  asm volatile("s_waitcnt vmcnt(9)\n\ts_barrier" ::: "memory");
  else if constexpr (N == 12) asm volatile("s_waitcnt vmcnt(12)\n\ts_barrier" ::: "memory");
}
__device__ __forceinline__ void bar_only() {
  asm volatile("s_barrier" ::: "memory");
}

// ---------------- init: zero output (incl aux loss) + counters ----------------
__global__ void zero_init_kernel(float* __restrict__ out, int n, int* __restrict__ cnt) {
  int i = blockIdx.x * 256 + threadIdx.x;
  if (i < n) out[i] = 0.0f;
  if (i < E_NUM) cnt[i] = 0;
}

// ---------------- convert x to bf16 ----------------
__global__ void convert_x_kernel(const float* __restrict__ x, u16* __restrict__ xbf) {
  int i = (blockIdx.x * 256 + threadIdx.x) * 8;
  float4 a = *(const float4*)(x + i);
  float4 b = *(const float4*)(x + i + 4);
  union { u16 s[8]; uint4 v; } o;
  o.s[0] = f2bf(a.x); o.s[1] = f2bf(a.y); o.s[2] = f2bf(a.z); o.s[3] = f2bf(a.w);
  o.s[4] = f2bf(b.x); o.s[5] = f2bf(b.y); o.s[6] = f2bf(b.z); o.s[7] = f2bf(b.w);
  *(uint4*)(xbf + i) = o.v;
}

// ---------------- W1 [E][C][D] f32 -> W1t [E][D][C] bf16 ----------------
__global__ void transpose_w1_kernel(const float* __restrict__ W1, u16* __restrict__ W1t) {
  __shared__ float t[32][33];
  const int e = blockIdx.z;
  const int d0 = blockIdx.x * 32, c0 = blockIdx.y * 32;
  const int tx = threadIdx.x, ty = threadIdx.y;
#pragma unroll
  for (int i = 0; i < 4; i++)
    t[ty + i * 8][tx] = W1[((size_t)e * C_DIM + c0 + ty + i * 8) * D_DIM + d0 + tx];
  __syncthreads();
#pragma unroll
  for (int i = 0; i < 4; i++)
    W1t[((size_t)e * D_DIM + d0 + ty + i * 8) * C_DIM + c0 + tx] = f2bf(t[tx][ty + i * 8]);
}

// ---------------- W2 [E][D][C] f32 -> W2t [E][C][D] bf16 ----------------
__global__ void transpose_w2_kernel(const float* __restrict__ W2, u16* __restrict__ W2t) {
  __shared__ float t[32][33];
  const int e = blockIdx.z;
  const int c0 = blockIdx.x * 32, d0 = blockIdx.y * 32;
  const int tx = threadIdx.x, ty = threadIdx.y;
#pragma unroll
  for (int i = 0; i < 4; i++)
    t[ty + i * 8][tx] = W2[((size_t)e * D_DIM + d0 + ty + i * 8) * C_DIM + c0 + tx];
  __syncthreads();
#pragma unroll
  for (int i = 0; i < 4; i++)
    W2t[((size_t)e * C_DIM + c0 + ty + i * 8) * D_DIM + d0 + tx] = f2bf(t[tx][ty + i * 8]);
}

// ---------------- router: logits (fp64), top-2, scatter ----------------
__global__ void router_kernel(const float* __restrict__ x, const float* __restrict__ rw,
                              int* __restrict__ cnt, int* __restrict__ list,
                              float* __restrict__ wl) {
  const int lane = threadIdx.x & 63;
  const int n = blockIdx.x * 4 + (threadIdx.x >> 6);
  const float* xr = x + (size_t)n * C_DIM;
  double acc[E_NUM];
#pragma unroll
  for (int e = 0; e < E_NUM; e++) acc[e] = 0.0;
  for (int c = lane; c < C_DIM; c += 64) {
    float xv = xr[c];
#pragma unroll
    for (int e = 0; e < E_NUM; e++) acc[e] += (double)xv * (double)rw[e * C_DIM + c];
  }
#pragma unroll
  for (int e = 0; e < E_NUM; e++) {
    double v = acc[e];
#pragma unroll
    for (int off = 32; off > 0; off >>= 1) v += __shfl_down(v, off, 64);
    acc[e] = v;
  }
  if (lane == 0) {
    int i0 = 0;
#pragma unroll
    for (int e = 1; e < E_NUM; e++) if (acc[e] > acc[i0]) i0 = e;
    int i1 = (i0 == 0) ? 1 : 0;
#pragma unroll
    for (int e = 0; e < E_NUM; e++) if (e != i0 && acc[e] > acc[i1]) i1 = e;
    double d = acc[i0] - acc[i1];          // >= 0
    double w0 = 1.0 / (1.0 + exp(-d));     // p0/(p0+p1)
    double w1 = 1.0 - w0;
    int p0 = atomicAdd(&cnt[i0], 1);
    list[i0 * N_TOK + p0] = n; wl[i0 * N_TOK + p0] = (float)w0;
    int p1 = atomicAdd(&cnt[i1], 1);
    list[i1 * N_TOK + p1] = n; wl[i1 * N_TOK + p1] = (float)w1;
  }
}

// ---------------- prefix sum + block table (BM=256 segments) ----------------
__global__ void prefix_kernel(const int* __restrict__ cnt, int* __restrict__ rowbase,
                              int* __restrict__ btab) {
  if (threadIdx.x == 0) {
    int s = 0, nb = 0;
    for (int e = 0; e < E_NUM; e++) {
      rowbase[e] = s;
      for (int m0 = 0; m0 < cnt[e]; m0 += 256) { btab[2 * nb] = e; btab[2 * nb + 1] = m0; nb++; }
      s += cnt[e];
    }
    for (; nb < MAXB; nb++) { btab[2 * nb] = -1; btab[2 * nb + 1] = 0; }
  }
}

// ---------------- 8-wave 256-row depth-3-pipelined GEMM (T1+T2+T3+T4+T5) ----------------
// EPI=1: h = gelu(Xg @ W1t^T + b1)    A=Xbf gathered rows, Wt=[E][D][C], N=D
// EPI=2: out += w*(h @ W2t^T + b2)    A=h contiguous rows,  Wt=[E][C][D], N=C
template<int BM, int BN, int EPI>
__global__ __launch_bounds__(512, 1) void gemm8p_kernel(
    const u16* __restrict__ A, const u16* __restrict__ Wt, const float* __restrict__ bias_,
    const int* __restrict__ btab, const int* __restrict__ cnt, const int* __restrict__ rowbase,
    const int* __restrict__ list, const float* __restrict__ wl,
    u16* __restrict__ hout, float* __restrict__ out) {
  constexpr int K    = (EPI == 1) ? C_DIM : D_DIM;
  constexpr int NTOT = (EPI == 1) ? D_DIM : C_DIM;
  constexpr int NB   = NTOT / BN;  // n0 tiles
  constexpr int NH   = K / 32;     // half-tiles (BK=32 per phase)
  constexpr int TM = BM / 2;       // 128 (2 M-waves)
  constexpr int TN = BN / 4;       // 64 / 32 (4 N-waves)
  constexpr int MR = TM / 16;      // 8
  constexpr int NR = TN / 16;      // 4 / 2
  constexpr int RA = BM / 128;     // stage gl_lds reps A = 2
  constexpr int RB = BN / 128;     // 2 / 1
  constexpr int VS = RA + RB;      // vmcnt per stage

  __shared__ __align__(16) u16 ldsA[4 * BM * 32];  // 4 half-tile slots
  __shared__ __align__(16) u16 ldsB[4 * BN * 32];

  // T1: bijective XCD swizzle (gridDim.x % 8 == 0); n0-minor order clusters
  // one expert's blocks (sharing A panels + weight slices) onto one XCD.
  const int q = gridDim.x >> 3;
  const int L = (blockIdx.x & 7) * q + (blockIdx.x >> 3);
  const int bx = L / NB;
  const int n0 = (L % NB) * BN;

  const int e = btab[bx * 2];
  if (e < 0) return;
  const int m0 = btab[bx * 2 + 1];
  const int count = cnt[e];
  const int rb = rowbase[e];

  const int tid = threadIdx.x;
  const int lane = tid & 63;
  const int wid = tid >> 6;
  const int wr = wid >> 2, wc = wid & 3;
  const int l15 = lane & 15, l4 = lane >> 4;

  // staging: thread handles 16B chunk c = tid + r*512; row=c>>2, pos=c&3.
  // T2 swizzle (involution): source chunk = pos ^ ((row>>1)&3); LDS dest linear.
  const int cs8 = ((tid & 3) ^ ((tid >> 3) & 3)) * 8;
  const int* lst = list + e * N_TOK;
  const u16* aptrs[RA];
#pragma unroll
  for (int r = 0; r < RA; r++) {
    const int arow = (tid + r * 512) >> 2;
    const int mm = min(m0 + arow, count - 1);
    const size_t rowi = (EPI == 1) ? (size_t)lst[mm] : (size_t)(rb + mm);
    aptrs[r] = A + rowi * K + cs8;
  }
  const u16* bptrs[RB];
#pragma unroll
  for (int r = 0; r < RB; r++) {
    const int brow = (tid + r * 512) >> 2;
    bptrs[r] = Wt + ((size_t)e * NTOT + n0 + brow) * K + cs8;
  }

  // fragment read offsets (swizzled): row*32 + ((chunk ^ ((row>>1)&3))*8
  const int swz = (l15 >> 1) & 3;
  const int paoff = (wr * TM + l15) * 32 + ((l4 ^ swz) * 8);
  const int pboff = (wc * TN + l15) * 32 + ((l4 ^ swz) * 8);

  f32x4 acc[MR][NR];
#pragma unroll
  for (int i = 0; i < MR; i++)
#pragma unroll
    for (int j = 0; j < NR; j++) acc[i][j] = {0.f, 0.f, 0.f, 0.f};

  auto STAGE = [&](int h) {   // stage half-tile h into slot h&3
    u16* da = ldsA + (h & 3) * (BM * 32) + tid * 8;
    u16* db = ldsB + (h & 3) * (BN * 32) + tid * 8;
    const int ko = h * 32;
#pragma unroll
    for (int r = 0; r < RA; r++) gl_lds16(aptrs[r] + ko, da + r * 4096);
#pragma unroll
    for (int r = 0; r < RB; r++) gl_lds16(bptrs[r] + ko, db + r * 4096);
  };

  auto PHASE = [&](int h) {
    const u16* pa = ldsA + (h & 3) * (BM * 32) + paoff;
    const u16* pb = ldsB + (h & 3) * (BN * 32) + pboff;
    bf16x8 av[MR], bv[NR];
#pragma unroll
    for (int i = 0; i < MR; i++) av[i] = *(const bf16x8*)(pa + i * 512);
#pragma unroll
    for (int j = 0; j < NR; j++) bv[j] = *(const bf16x8*)(pb + j * 512);
    __builtin_amdgcn_s_setprio(1);
#pragma unroll
    for (int i = 0; i < MR; i++)
#pragma unroll
      for (int j = 0; j < NR; j++)
        acc[i][j] = __builtin_amdgcn_mfma_f32_16x16x32_bf16(av[i], bv[j], acc[i][j], 0, 0, 0);
    __builtin_amdgcn_s_setprio(0);
  };

  // prologue: 3 half-tiles in flight (T4: counted vmcnt, never 0 in main loop)
  STAGE(0); STAGE(1); STAGE(2);
  for (int h = 0; h < NH - 3; ++h) {
    STAGE(h + 3);         // slot (h+3)&3 == (h-1)&3, released by prev iter's end-barrier
    wait_bar<3 * VS>();   // half-tile h landed (h+1..h+3 may fly)
    PHASE(h);
    bar_only();           // release slot h for overwrite next iteration
  }
  wait_bar<2 * VS>(); PHASE(NH - 3); bar_only();
  wait_bar<VS>();     PHASE(NH - 2); bar_only();
  wait_bar<0>();      PHASE(NH - 1);

  // ---------------- epilogue ----------------
  if constexpr (EPI == 1) {
#pragma unroll
    for (int i = 0; i < MR; i++) {
      const int rloc = wr * TM + i * 16 + l4 * 4;
#pragma unroll
      for (int j = 0; j < NR; j++) {
        const int col = n0 + wc * TN + j * 16 + l15;
        const float bias = bias_[e * NTOT + col];
#pragma unroll
        for (int r = 0; r < 4; r++) {
          const int m = m0 + rloc + r;
          if (m < count) {
            float v = acc[i][j][r] + bias;
            float g = 0.5f * v * (1.0f + erff(v * 0.70710678118654752f));
            hout[(size_t)(rb + m) * D_DIM + col] = f2bf(g);
          }
        }
      }
    }
  } else {
    const float* wlst = wl + e * N_TOK;
#pragma unroll
    for (int i = 0; i < MR; i++) {
      const int rloc = wr * TM + i * 16 + l4 * 4;
#pragma unroll
      for (int j = 0; j < NR; j++) {
        const int col = n0 + wc * TN + j * 16 + l15;
        const float bias = bias_[e * NTOT + col];
#pragma unroll
        for (int r = 0; r < 4; r++) {
          const int m = m0 + rloc + r;
          if (m < count) {
            const int tk = lst[m];
            atomicAdd(out + (size_t)tk * C_DIM + col, wlst[m] * (acc[i][j][r] + bias));
          }
        }
      }
    }
  }
}

extern "C" void kernel_launch(void* const* d_in, const int* in_sizes, int n_in,
                              void* d_out, int out_size, void* d_ws, size_t ws_size,
                              hipStream_t stream) {
  const float* x  = (const float*)d_in[0];
  const float* rw = (const float*)d_in[1];
  const float* W1 = (const float*)d_in[2];
  const float* b1 = (const float*)d_in[3];
  const float* W2 = (const float*)d_in[4];
  const float* b2 = (const float*)d_in[5];
  float* out = (float*)d_out;

  char* ws = (char*)d_ws;
  u16* W1t    = (u16*)(ws);                      // 50,331,648 B
  u16* W2t    = (u16*)(ws + 50331648);           // 50,331,648 B
  u16* Xbf    = (u16*)(ws + 100663296);          // 16,777,216 B
  int* cnt    = (int*)(ws + 117440512);          // 256 B
  int* rowbase= (int*)(ws + 117440768);          // 256 B
  int* list   = (int*)(ws + 117441024);          // 262,144 B
  float* wl   = (float*)(ws + 117703168);        // 262,144 B
  int* btab   = (int*)(ws + 117965312);          // 1,024 B
  u16* h      = (u16*)(ws + 117966336);          // 100,663,296 B -> end 218,629,632

  zero_init_kernel<<<(out_size + 255) / 256, 256, 0, stream>>>(out, out_size, cnt);
  convert_x_kernel<<<(N_TOK * C_DIM) / (256 * 8), 256, 0, stream>>>(x, Xbf);
  transpose_w1_kernel<<<dim3(D_DIM / 32, C_DIM / 32, E_NUM), dim3(32, 8), 0, stream>>>(W1, W1t);
  transpose_w2_kernel<<<dim3(C_DIM / 32, D_DIM / 32, E_NUM), dim3(32, 8), 0, stream>>>(W2, W2t);
  router_kernel<<<N_TOK / 4, 256, 0, stream>>>(x, rw, cnt, list, wl);
  prefix_kernel<<<1, 64, 0, stream>>>(cnt, rowbase, btab);
  gemm8p_kernel<256, 256, 1><<<MAXB * (D_DIM / 256), 512, 0, stream>>>(
      Xbf, W1t, b1, btab, cnt, rowbase, list, wl, h, out);
  gemm8p_kernel<256, 128, 2><<<MAXB * (C_DIM / 128), 512, 0, stream>>>(
      h, W2t, b2, btab, cnt, rowbase, list, wl, h, out);
}